// Round 6
// baseline (1412.301 us; speedup 1.0000x reference)
//
#include <hip/hip_runtime.h>

#define M 256     // rows of S (n_hos*n_types)
#define N 4096    // cols of S (n_structs)
#define NIT 200   // PDHG iterations
#define PIT 30    // power iterations
#define CSRCAP 131072

// z_s dummy: float2 slot N (byte 32768, fits u16, kept zero)
#define ZDUMMY (N*8)

// ---------------- counts ----------------
__global__ void k_colcnt(const float* __restrict__ S, int* __restrict__ col_cnt){
  int j = blockIdx.x*256 + threadIdx.x;
  int c = 0;
  for (int i = 0; i < M; ++i) c += (S[i*N + j] != 0.0f) ? 1 : 0;
  col_cnt[j] = c;
}

__global__ void k_rowcnt(const float* __restrict__ S, int* __restrict__ row_cnt){
  int wid = blockIdx.x*(blockDim.x>>6) + (threadIdx.x>>6);
  int l = threadIdx.x & 63;
  if (wid >= M) return;
  int cnt = 0;
  for (int jc = 0; jc < N/64; ++jc){
    float v = S[wid*N + jc*64 + l];
    unsigned long long mask = __ballot(v != 0.0f);
    cnt += __popcll(mask);
  }
  if (l == 0) row_cnt[wid] = cnt;
}

// ---------------- deterministic rank sort by (cnt, index) ----------------
__global__ void k_sortcol(const int* __restrict__ col_cnt,
                          int* __restrict__ col_perm, int* __restrict__ col_rank){
  __shared__ int cs[N];
  int t0 = threadIdx.x;
  for (int t = 0; t < N/256; ++t) cs[t0 + 256*t] = col_cnt[t0 + 256*t];
  __syncthreads();
  int j = blockIdx.x*256 + t0;
  int cj = cs[j];
  int rank = 0;
  #pragma unroll 4
  for (int jj = 0; jj < N; ++jj){
    int c = cs[jj];
    rank += ((c < cj) || (c == cj && jj < j)) ? 1 : 0;
  }
  col_perm[rank] = j;
  col_rank[j] = rank;
}

__global__ void k_sortrow(const int* __restrict__ row_cnt,
                          int* __restrict__ row_perm, int* __restrict__ row_ptr){
  int i = threadIdx.x;
  int ci = row_cnt[i];
  int rank = 0, pre = 0;
  for (int ii = 0; ii < M; ++ii){
    int c = row_cnt[ii];
    bool less = (c < ci) || (c == ci && ii < i);
    rank += less ? 1 : 0;
    pre  += less ? c : 0;
  }
  row_perm[rank] = i;
  row_ptr[rank]  = pre;
}

// ---------------- CSR fill (z float2-slot byte offsets) ----------------
__global__ void k_fillcsr(const float* __restrict__ S, const int* __restrict__ row_perm,
                          const int* __restrict__ row_ptr, unsigned short* __restrict__ csr){
  int rr = blockIdx.x*(blockDim.x>>6) + (threadIdx.x>>6);
  int l = threadIdx.x & 63;
  if (rr >= M) return;
  int i = row_perm[rr];
  int pos = row_ptr[rr];
  for (int jc = 0; jc < N/64; ++jc){
    float v = S[i*N + jc*64 + l];
    unsigned long long mask = __ballot(v != 0.0f);
    if (v != 0.0f){
      int off = __popcll(mask & ((1ull << l) - 1ull));
      int p = pos + off;
      if (p < CSRCAP) csr[p] = (unsigned short)((jc*64 + l)*8);
    }
    pos += __popcll(mask);
  }
}

// ---------------- wave-trip counts + base offsets (TRIP units) ----------
__global__ void k_trips(const int* __restrict__ col_cnt, const int* __restrict__ col_perm,
                        const int* __restrict__ row_cnt, const int* __restrict__ row_perm,
                        int* __restrict__ pT4, int* __restrict__ pB4,
                        int* __restrict__ dT4, int* __restrict__ dB4){
  int tid = threadIdx.x;
  if (tid < 64){
    int k = tid >> 4, w = tid & 15;
    int mx = 0;
    for (int l = 0; l < 64; ++l){
      int s = 64*w + l + 1024*k;
      int c = col_cnt[col_perm[s]];
      mx = max(mx, c);
    }
    pT4[tid] = min((mx + 3) >> 2, 16);
  } else if (tid < 80){
    int w = tid - 64;
    int mx = 0;
    for (int l = 0; l < 64; ++l){
      int t = w*64 + l;
      int r = t >> 2, q = t & 3;
      int len = row_cnt[row_perm[r]];
      int qs = (len*q) >> 2, qe = (len*(q+1)) >> 2;
      mx = max(mx, qe - qs);
    }
    dT4[w] = min((mx + 3) >> 2, 80);
  }
  __syncthreads();
  if (tid == 0){
    int acc = 0;
    for (int i = 0; i < 64; ++i){ pB4[i] = acc; acc += pT4[i]; }
    acc = 0;
    for (int i = 0; i < 16; ++i){ dB4[i] = acc; acc += dT4[i]; }
  }
}

// ---------------- primal stream fill: y_rep byte offsets ----------------
// y_rep[i][s] at byte i*256 + s*8. Lane l reads replica s = l&31, deviating
// by +17 when s would hit the per-row zero slot (s == i&31).
// Dummy = byte 0 (row 0's zero slot, always 0).
__global__ void k_fillp(const float* __restrict__ S, const int* __restrict__ col_rank,
                        const int* __restrict__ pT4, const int* __restrict__ pB4,
                        unsigned short* __restrict__ pstream){
  int j = blockIdx.x*256 + threadIdx.x;
  int sr = col_rank[j];
  int k = sr >> 10, rem = sr & 1023, w = rem >> 6, l = rem & 63;
  int kw = k*16 + w;
  int base = pB4[kw];
  int cap = pT4[kw]*4;
  int ls = l & 31;
  int t = 0;
  for (int i = 0; i < M && t < cap; ++i){
    if (S[i*N + j] != 0.0f){
      int s = ls;
      if (s == (i & 31)) s = (s + 17) & 31;
      pstream[((base + (t>>2))*64 + l)*4 + (t&3)] = (unsigned short)(i*256 + s*8);
      ++t;
    }
  }
  for (; t < cap; ++t)
    pstream[((base + (t>>2))*64 + l)*4 + (t&3)] = (unsigned short)0;
}

// ---------------- dual stream fill (z byte offsets) ----------------
__global__ void k_filld(const unsigned short* __restrict__ csr,
                        const int* __restrict__ row_cnt, const int* __restrict__ row_perm,
                        const int* __restrict__ row_ptr,
                        const int* __restrict__ dT4, const int* __restrict__ dB4,
                        unsigned short* __restrict__ dstream){
  int tid = blockIdx.x*256 + threadIdx.x;   // 1024 total, same mapping as k_main
  int w = tid >> 6, l = tid & 63;
  int r = tid >> 2, q = tid & 3;
  int len = row_cnt[row_perm[r]];
  int rb = row_ptr[r];
  int qs = (len*q) >> 2, qe = (len*(q+1)) >> 2;
  int base = dB4[w];
  int cap = dT4[w]*4;
  int qlen = qe - qs; if (qlen > cap) qlen = cap;
  int t = 0;
  for (; t < qlen; ++t)
    dstream[((base + (t>>2))*64 + l)*4 + (t&3)] = csr[rb + qs + t];
  for (; t < cap; ++t)
    dstream[((base + (t>>2))*64 + l)*4 + (t&3)] = (unsigned short)ZDUMMY;
}

// ---------------- persistent PDHG (+ fused power iteration) ------------
// One block per 2 batch elements. y replicated 32x so primal gathers have
// lane-determined banks (4-phase floor).
__global__ __launch_bounds__(1024) void k_main(
    const float* __restrict__ X,
    const ushort4* __restrict__ pstream, const ushort4* __restrict__ dstream,
    const int* __restrict__ col_perm, const int* __restrict__ row_perm,
    const int* __restrict__ pT4, const int* __restrict__ pB4,
    const int* __restrict__ dT4, const int* __restrict__ dB4,
    float* __restrict__ out)
{
  __shared__ float2 y_rep[M*32];    // 64 KB, [i][s] = y[i] (s != i&31), zero slot at s==i&31
  __shared__ float2 z_s[N+8];       // 32 KB (+dummy at N)
  __shared__ float2 part[1024];     // reduction scratch
  const int tid = threadIdx.x, w = tid >> 6, l = tid & 63;
  const int b0 = blockIdx.x * 2;

  int cj[4], pb[4], pt[4];
  #pragma unroll
  for (int k = 0; k < 4; ++k){
    int kw = k*16 + w;
    pb[k] = pB4[kw]; pt[k] = pT4[kw];
    cj[k] = col_perm[tid + 1024*k];
  }
  const int r = tid >> 2, q = tid & 3;
  const int rid = row_perm[r];
  const int db = dB4[w], dt = dT4[w];
  const int zslot = rid & 31;       // this row's permanent-zero replica
  float2 bi;
  bi.x = X[b0*M + rid];             // all 4 q-lanes hold the row rhs
  bi.y = X[(b0+1)*M + rid];

  // ---- init: v = ones in z (both lanes), y_rep = 0
  #pragma unroll
  for (int k = 0; k < 4; ++k) z_s[cj[k]] = make_float2(1.0f, 1.0f);
  #pragma unroll
  for (int t = 0; t < 8; ++t) y_rep[tid + 1024*t] = make_float2(0.0f, 0.0f);
  if (tid < 8) z_s[N+tid] = make_float2(0.0f, 0.0f);
  __syncthreads();

  const char* yb = (const char*)y_rep;
  const char* zb = (const char*)z_s;

  // ---- power iteration: v <- (S^T S v)/1024; L = sqrt(||Sv||^2/||v||^2)
  float tl[4];
  #pragma unroll
  for (int k = 0; k < 4; ++k) tl[k] = 0.0f;

  for (int it = 0; it < PIT; ++it){
    // u = S v  (dual-style gather of z)
    float a = 0.0f;
    for (int c = 0; c < dt; ++c){
      ushort4 ix = dstream[(db + c)*64 + l];
      a += ((const float2*)(zb + ix.x))->x + ((const float2*)(zb + ix.y))->x
         + ((const float2*)(zb + ix.z))->x + ((const float2*)(zb + ix.w))->x;
    }
    a += __shfl_xor(a, 1);
    a += __shfl_xor(a, 2);
    // replicated u-write (banks = f(slot), 4-phase)
    #pragma unroll
    for (int t = 0; t < 8; ++t){
      int s = (q << 3) | ((t + r) & 7);
      if (s != zslot) y_rep[rid*32 + s] = make_float2(a, a);
    }
    __syncthreads();
    // v = (S^T u)/1024  (primal-style gather of y_rep)
    #pragma unroll
    for (int k = 0; k < 4; ++k){
      float a2 = 0.0f;
      for (int c = 0; c < pt[k]; ++c){
        ushort4 ix = pstream[(pb[k] + c)*64 + l];
        a2 += ((const float2*)(yb + ix.x))->x + ((const float2*)(yb + ix.y))->x
            + ((const float2*)(yb + ix.z))->x + ((const float2*)(yb + ix.w))->x;
      }
      tl[k] = a2 * (1.0f/1024.0f);
      z_s[cj[k]] = make_float2(tl[k], tl[k]);
    }
    __syncthreads();
  }

  // Rayleigh: L^2 = ||S v||^2 / ||v||^2
  float pv = 0.0f;
  #pragma unroll
  for (int k = 0; k < 4; ++k) pv += tl[k]*tl[k];
  {
    float a = 0.0f;
    for (int c = 0; c < dt; ++c){
      ushort4 ix = dstream[(db + c)*64 + l];
      a += ((const float2*)(zb + ix.x))->x + ((const float2*)(zb + ix.y))->x
         + ((const float2*)(zb + ix.z))->x + ((const float2*)(zb + ix.w))->x;
    }
    a += __shfl_xor(a, 1);
    a += __shfl_xor(a, 2);
    float fsq = (q == 0) ? a*a : 0.0f;
    part[tid] = make_float2(pv, fsq);
  }
  __syncthreads();
  for (int sd = 512; sd > 0; sd >>= 1){
    if (tid < sd){
      part[tid].x += part[tid+sd].x;
      part[tid].y += part[tid+sd].y;
    }
    __syncthreads();
  }
  const float tau = 0.9f * sqrtf(part[0].x / part[0].y);
  const float sigma = tau;
  __syncthreads();

  // ---- reset state for PDHG
  #pragma unroll
  for (int t = 0; t < 8; ++t) y_rep[tid + 1024*t] = make_float2(0.0f, 0.0f);
  float2 x[4];
  #pragma unroll
  for (int k = 0; k < 4; ++k) x[k] = make_float2(0.0f, 0.0f);
  float2 yv = make_float2(0.0f, 0.0f);
  __syncthreads();

  // ---- PDHG main loop
  for (int it = 0; it < NIT; ++it){
    const bool last = (it == NIT-1);
    // primal: x+ = max(x + tau*(1 - y S), 0); z = 2 x+ - x
    #pragma unroll
    for (int k = 0; k < 4; ++k){
      float ax = 0.0f, ay = 0.0f;
      for (int c = 0; c < pt[k]; ++c){
        ushort4 ix = pstream[(pb[k] + c)*64 + l];
        float2 a0 = *(const float2*)(yb + ix.x);
        float2 a1 = *(const float2*)(yb + ix.y);
        float2 a2 = *(const float2*)(yb + ix.z);
        float2 a3 = *(const float2*)(yb + ix.w);
        ax += (a0.x + a1.x) + (a2.x + a3.x);
        ay += (a0.y + a1.y) + (a2.y + a3.y);
      }
      float2 xo = x[k];
      float xnx = fmaxf(xo.x + tau*(1.0f - ax), 0.0f);
      float xny = fmaxf(xo.y + tau*(1.0f - ay), 0.0f);
      if (!last) z_s[cj[k]] = make_float2(2.0f*xnx - xo.x, 2.0f*xny - xo.y);
      x[k] = make_float2(xnx, xny);
    }
    if (last) break;
    __syncthreads();
    // dual: quarter-row gathers + in-wave reduce; replicated y-write
    float ax = 0.0f, ay = 0.0f;
    for (int c = 0; c < dt; ++c){
      ushort4 ix = dstream[(db + c)*64 + l];
      float2 a0 = *(const float2*)(zb + ix.x);
      float2 a1 = *(const float2*)(zb + ix.y);
      float2 a2 = *(const float2*)(zb + ix.z);
      float2 a3 = *(const float2*)(zb + ix.w);
      ax += (a0.x + a1.x) + (a2.x + a3.x);
      ay += (a0.y + a1.y) + (a2.y + a3.y);
    }
    ax += __shfl_xor(ax, 1);  ay += __shfl_xor(ay, 1);
    ax += __shfl_xor(ax, 2);  ay += __shfl_xor(ay, 2);
    yv.x = fmaxf(yv.x + sigma*(ax - bi.x), 0.0f);
    yv.y = fmaxf(yv.y + sigma*(ay - bi.y), 0.0f);
    #pragma unroll
    for (int t = 0; t < 8; ++t){
      int s = (q << 3) | ((t + r) & 7);
      if (s != zslot) y_rep[rid*32 + s] = yv;
    }
    __syncthreads();
  }

  #pragma unroll
  for (int k = 0; k < 4; ++k){
    out[(size_t)b0*N + cj[k]]     = x[k].x;
    out[(size_t)(b0+1)*N + cj[k]] = x[k].y;
  }
}

// ---------------- launcher ----------------
extern "C" void kernel_launch(void* const* d_in, const int* in_sizes, int n_in,
                              void* d_out, int out_size, void* d_ws, size_t ws_size,
                              hipStream_t stream)
{
  const float* X = (const float*)d_in[0];   // [B, 16, 16] -> b
  const float* S = (const float*)d_in[1];   // [M, N]
  float* out = (float*)d_out;               // [B, N] fp32
  const int B = in_sizes[0] / M;            // 512

  char* p = (char*)d_ws;
  auto alloc = [&](size_t bytes)->char*{
    char* q = p; p += (bytes + 255) & ~size_t(255); return q;
  };
  int* col_cnt  = (int*)alloc(N*sizeof(int));
  int* col_perm = (int*)alloc(N*sizeof(int));
  int* col_rank = (int*)alloc(N*sizeof(int));
  int* row_cnt  = (int*)alloc(M*sizeof(int));
  int* row_perm = (int*)alloc(M*sizeof(int));
  int* row_ptr  = (int*)alloc(M*sizeof(int));
  int* pT4      = (int*)alloc(64*sizeof(int));
  int* pB4      = (int*)alloc(64*sizeof(int));
  int* dT4      = (int*)alloc(16*sizeof(int));
  int* dB4      = (int*)alloc(16*sizeof(int));
  unsigned short* csr     = (unsigned short*)alloc(CSRCAP*sizeof(unsigned short));
  unsigned short* pstream = (unsigned short*)alloc(65536ull*8);
  unsigned short* dstream = (unsigned short*)alloc(81920ull*8);

  k_colcnt <<<N/256, 256, 0, stream>>>(S, col_cnt);
  k_rowcnt <<<16, 1024, 0, stream>>>(S, row_cnt);
  k_sortcol<<<N/256, 256, 0, stream>>>(col_cnt, col_perm, col_rank);
  k_sortrow<<<1, M, 0, stream>>>(row_cnt, row_perm, row_ptr);
  k_fillcsr<<<16, 1024, 0, stream>>>(S, row_perm, row_ptr, csr);
  k_trips  <<<1, 256, 0, stream>>>(col_cnt, col_perm, row_cnt, row_perm, pT4, pB4, dT4, dB4);
  k_fillp  <<<N/256, 256, 0, stream>>>(S, col_rank, pT4, pB4, pstream);
  k_filld  <<<4, 256, 0, stream>>>(csr, row_cnt, row_perm, row_ptr, dT4, dB4, dstream);
  k_main   <<<B/2, 1024, 0, stream>>>(X, (const ushort4*)pstream, (const ushort4*)dstream,
                                      col_perm, row_perm, pT4, pB4, dT4, dB4, out);
}

// Round 7
// 1300.926 us; speedup vs baseline: 1.0856x; 1.0856x over previous
//
#include <hip/hip_runtime.h>

#define M 256     // rows of S (n_hos*n_types)
#define N 4096    // cols of S (n_structs)
#define NIT 200   // PDHG iterations
#define PIT 30    // power iterations

// dummy byte-offsets (float2 slots): y_s[256], z_s[4096]
#define YDUMMY (256*8)
#define ZDUMMY (4096*8)

// ---------------- counts ----------------
__global__ void k_colcnt(const float* __restrict__ S, int* __restrict__ col_cnt){
  int j = blockIdx.x*256 + threadIdx.x;
  int c = 0;
  for (int i = 0; i < M; ++i) c += (S[i*N + j] != 0.0f) ? 1 : 0;
  col_cnt[j] = c;
}

__global__ void k_rowcnt(const float* __restrict__ S, int* __restrict__ row_cnt){
  int wid = blockIdx.x*(blockDim.x>>6) + (threadIdx.x>>6);
  int l = threadIdx.x & 63;
  if (wid >= M) return;
  int cnt = 0;
  for (int jc = 0; jc < N/64; ++jc){
    float v = S[wid*N + jc*64 + l];
    unsigned long long mask = __ballot(v != 0.0f);
    cnt += __popcll(mask);
  }
  if (l == 0) row_cnt[wid] = cnt;
}

// ---------------- deterministic rank sort by (cnt, index) ----------------
__global__ void k_sortcol(const int* __restrict__ col_cnt,
                          int* __restrict__ col_perm, int* __restrict__ col_rank){
  __shared__ int cs[N];
  int t0 = threadIdx.x;
  for (int t = 0; t < N/256; ++t) cs[t0 + 256*t] = col_cnt[t0 + 256*t];
  __syncthreads();
  int j = blockIdx.x*256 + t0;
  int cj = cs[j];
  int rank = 0;
  #pragma unroll 4
  for (int jj = 0; jj < N; ++jj){
    int c = cs[jj];
    rank += ((c < cj) || (c == cj && jj < j)) ? 1 : 0;
  }
  col_perm[rank] = j;
  col_rank[j] = rank;
}

__global__ void k_sortrow(const int* __restrict__ row_cnt,
                          int* __restrict__ row_perm, int* __restrict__ row_rank){
  int i = threadIdx.x;
  int ci = row_cnt[i];
  int rank = 0;
  for (int ii = 0; ii < M; ++ii){
    int c = row_cnt[ii];
    rank += ((c < ci) || (c == ci && ii < i)) ? 1 : 0;
  }
  row_perm[rank] = i;
  row_rank[i] = rank;
}

// ---------------- wave-trip counts + base offsets (TRIP units) ----------
__global__ void k_trips(const int* __restrict__ col_cnt, const int* __restrict__ col_perm,
                        const int* __restrict__ row_cnt, const int* __restrict__ row_perm,
                        int* __restrict__ pT4, int* __restrict__ pB4,
                        int* __restrict__ dT4, int* __restrict__ dB4){
  int tid = threadIdx.x;
  if (tid < 64){
    int k = tid >> 4, w = tid & 15;
    int mx = 0;
    for (int l = 0; l < 64; ++l){
      int s = 64*w + l + 1024*k;
      int c = col_cnt[col_perm[s]];
      mx = max(mx, c);
    }
    pT4[tid] = min((mx + 3) >> 2, 16);
  } else if (tid < 80){
    int w = tid - 64;
    int mx = 0;
    for (int l = 0; l < 64; ++l){
      int t = w*64 + l;
      int r = t >> 2, q = t & 3;
      int len = row_cnt[row_perm[r]];
      int qs = (len*q) >> 2, qe = (len*(q+1)) >> 2;
      mx = max(mx, qe - qs);
    }
    dT4[w] = min((mx + 3) >> 2, 80);
  }
  __syncthreads();
  if (tid == 0){
    int acc = 0;
    for (int i = 0; i < 64; ++i){ pB4[i] = acc; acc += pT4[i]; }
    acc = 0;
    for (int i = 0; i < 16; ++i){ dB4[i] = acc; acc += dT4[i]; }
  }
}

// ---------------- primal stream fill: class-rotated emit ----------------
// Bank class of y slot i = i mod 16. Lane l starts at class l&15 so each
// gather instruction's 64 lanes start 4-per-class (b64 floor = 4 cyc).
__global__ void k_fillp(const float* __restrict__ S, const int* __restrict__ col_rank,
                        const int* __restrict__ pT4, const int* __restrict__ pB4,
                        unsigned short* __restrict__ pstream){
  int j = blockIdx.x*256 + threadIdx.x;
  int sr = col_rank[j];
  int k = sr >> 10, rem = sr & 1023, w = rem >> 6, l = rem & 63;
  int kw = k*16 + w;
  int base = pB4[kw];
  int cap = pT4[kw]*4;
  int T = l & 15;
  int t = 0;
  for (int cc = 0; cc < 16 && t < cap; ++cc){
    int c = (T + cc) & 15;
    for (int i16 = 0; i16 < 16 && t < cap; ++i16){
      int i = i16*16 + c;                  // i mod 16 == c
      if (S[i*N + j] != 0.0f){
        pstream[((base + (t>>2))*64 + l)*4 + (t&3)] = (unsigned short)(i*8);
        ++t;
      }
    }
  }
  for (; t < cap; ++t)
    pstream[((base + (t>>2))*64 + l)*4 + (t&3)] = (unsigned short)YDUMMY;
}

// ---------------- dual stream fill: class-rotated, wave per row ----------
// One 64-thread block per sorted row slot rr. Emits row's nnz in class
// order starting at class rr&15, contiguous quarter-split to 4 consumer
// lanes l_c = (rr&15)*4 + q.
__global__ void k_filld(const float* __restrict__ S,
                        const int* __restrict__ row_cnt, const int* __restrict__ row_perm,
                        const int* __restrict__ dT4, const int* __restrict__ dB4,
                        unsigned short* __restrict__ dstream){
  int rr = blockIdx.x;                 // sorted row slot 0..255
  int lf = threadIdx.x;                // 0..63
  int i  = row_perm[rr];
  int len = row_cnt[i];
  int c0 = rr & 15;
  int wc = rr >> 4;                    // consumer wave
  int base = dB4[wc];
  int cap  = dT4[wc]*4;
  int qs1 = (len*1) >> 2, qs2 = (len*2) >> 2, qs3 = (len*3) >> 2;
  int lc0 = (rr & 15) << 2;            // consumer lane base

  int pos = 0;
  for (int cc = 0; cc < 16; ++cc){
    int c = (c0 + cc) & 15;
    for (int mc = 0; mc < 4; ++mc){
      int m = mc*64 + lf;              // j = c + 16*m, j mod 16 == c
      int j = c + 16*m;
      float v = S[i*N + j];
      unsigned long long mask = __ballot(v != 0.0f);
      if (v != 0.0f){
        int rank = pos + __popcll(mask & ((1ull << lf) - 1ull));
        int q = (rank >= qs1) + (rank >= qs2) + (rank >= qs3);
        int qs = (q==0) ? 0 : ((q==1) ? qs1 : ((q==2) ? qs2 : qs3));
        int t = rank - qs;
        if (t < cap)
          dstream[((base + (t>>2))*64 + (lc0 + q))*4 + (t&3)] = (unsigned short)(j*8);
      }
      pos += __popcll(mask);
    }
  }
  // pad tails with dummy (z slot N, kept zero)
  if (lf < 4){
    int q = lf;
    int qs = (q==0) ? 0 : ((q==1) ? qs1 : ((q==2) ? qs2 : qs3));
    int qe = (q==3) ? len : ((q==0) ? qs1 : ((q==1) ? qs2 : qs3));
    int qlen = qe - qs; if (qlen > cap) qlen = cap;
    for (int t = qlen; t < cap; ++t)
      dstream[((base + (t>>2))*64 + (lc0 + q))*4 + (t&3)] = (unsigned short)ZDUMMY;
  }
}

// ---------------- power iteration (no per-step normalize) ---------------
__global__ __launch_bounds__(1024) void k_power(
    const ushort4* __restrict__ pstream, const ushort4* __restrict__ dstream,
    const int* __restrict__ col_perm, const int* __restrict__ row_perm,
    const int* __restrict__ pT4, const int* __restrict__ pB4,
    const int* __restrict__ dT4, const int* __restrict__ dB4,
    float* __restrict__ tauw)
{
  __shared__ float2 v_s[N+8];
  __shared__ float2 u_s[M+8];
  __shared__ float2 red2[1024];
  const int tid = threadIdx.x, w = tid >> 6, l = tid & 63;

  int cj[4], pb[4], pt[4];
  float tl[4];
  #pragma unroll
  for (int k = 0; k < 4; ++k){
    int kw = k*16 + w;
    pb[k] = pB4[kw]; pt[k] = pT4[kw];
    cj[k] = col_perm[tid + 1024*k];
    v_s[cj[k]] = make_float2(1.0f, 0.0f);
    tl[k] = 0.0f;
  }
  const int r = tid >> 2, q = tid & 3;
  const int rid = row_perm[r];
  const int db = dB4[w], dt = dT4[w];
  if (tid < 8){ v_s[N+tid] = make_float2(0,0); u_s[M+tid] = make_float2(0,0); }
  __syncthreads();

  const char* vb = (const char*)v_s;
  const char* ub = (const char*)u_s;

  for (int it = 0; it < PIT; ++it){
    float a = 0.0f;
    for (int c = 0; c < dt; ++c){
      ushort4 ix = dstream[(db + c)*64 + l];
      a += ((const float2*)(vb + ix.x))->x + ((const float2*)(vb + ix.y))->x
         + ((const float2*)(vb + ix.z))->x + ((const float2*)(vb + ix.w))->x;
    }
    a += __shfl_xor(a, 1);
    a += __shfl_xor(a, 2);
    if (q == 0) u_s[rid] = make_float2(a, 0.0f);
    __syncthreads();
    #pragma unroll
    for (int k = 0; k < 4; ++k){
      float a2 = 0.0f;
      for (int c = 0; c < pt[k]; ++c){
        ushort4 ix = pstream[(pb[k] + c)*64 + l];
        a2 += ((const float2*)(ub + ix.x))->x + ((const float2*)(ub + ix.y))->x
            + ((const float2*)(ub + ix.z))->x + ((const float2*)(ub + ix.w))->x;
      }
      tl[k] = a2 * (1.0f/1024.0f);
      v_s[cj[k]] = make_float2(tl[k], 0.0f);
    }
    __syncthreads();
  }

  float pv = 0.0f;
  #pragma unroll
  for (int k = 0; k < 4; ++k) pv += tl[k]*tl[k];
  float a = 0.0f;
  for (int c = 0; c < dt; ++c){
    ushort4 ix = dstream[(db + c)*64 + l];
    a += ((const float2*)(vb + ix.x))->x + ((const float2*)(vb + ix.y))->x
       + ((const float2*)(vb + ix.z))->x + ((const float2*)(vb + ix.w))->x;
  }
  a += __shfl_xor(a, 1);
  a += __shfl_xor(a, 2);
  float fsq = (q == 0) ? a*a : 0.0f;
  red2[tid] = make_float2(pv, fsq);
  __syncthreads();
  for (int sd = 512; sd > 0; sd >>= 1){
    if (tid < sd){
      red2[tid].x += red2[tid+sd].x;
      red2[tid].y += red2[tid+sd].y;
    }
    __syncthreads();
  }
  if (tid == 0) tauw[0] = 0.9f * sqrtf(red2[0].x / red2[0].y);
}

// ---------------- persistent PDHG: one block per 2 batches --------------
__global__ __launch_bounds__(1024) void k_main(
    const float* __restrict__ X,
    const ushort4* __restrict__ pstream, const ushort4* __restrict__ dstream,
    const int* __restrict__ col_perm, const int* __restrict__ row_perm,
    const int* __restrict__ pT4, const int* __restrict__ pB4,
    const int* __restrict__ dT4, const int* __restrict__ dB4,
    const float* __restrict__ tauw, float* __restrict__ out)
{
  __shared__ float2 z_s[N+8];
  __shared__ float2 y_s[M+8];
  const int tid = threadIdx.x, w = tid >> 6, l = tid & 63;
  const int b0 = blockIdx.x * 2;
  const float tau = tauw[0];
  const float sigma = tau;

  int cj[4], pb[4], pt[4];
  float2 x[4];
  #pragma unroll
  for (int k = 0; k < 4; ++k){
    int kw = k*16 + w;
    pb[k] = pB4[kw]; pt[k] = pT4[kw];
    cj[k] = col_perm[tid + 1024*k];
    x[k] = make_float2(0.0f, 0.0f);
  }
  const int r = tid >> 2, q = tid & 3;
  const int rid = row_perm[r];
  const int db = dB4[w], dt = dT4[w];
  float2 bi = make_float2(0,0), yv = make_float2(0,0);
  if (q == 0){
    bi.x = X[b0*M + rid];
    bi.y = X[(b0+1)*M + rid];
    y_s[rid] = make_float2(0,0);
  }
  if (tid < 8){ y_s[M+tid] = make_float2(0,0); z_s[N+tid] = make_float2(0,0); }
  __syncthreads();

  const char* yb = (const char*)y_s;
  const char* zb = (const char*)z_s;

  for (int it = 0; it < NIT; ++it){
    const bool last = (it == NIT-1);
    // primal: x+ = max(x + tau*(1 - y S), 0); z = 2 x+ - x
    #pragma unroll
    for (int k = 0; k < 4; ++k){
      float ax = 0.0f, ay = 0.0f;
      for (int c = 0; c < pt[k]; ++c){
        ushort4 ix = pstream[(pb[k] + c)*64 + l];
        float2 a0 = *(const float2*)(yb + ix.x);
        float2 a1 = *(const float2*)(yb + ix.y);
        float2 a2 = *(const float2*)(yb + ix.z);
        float2 a3 = *(const float2*)(yb + ix.w);
        ax += (a0.x + a1.x) + (a2.x + a3.x);
        ay += (a0.y + a1.y) + (a2.y + a3.y);
      }
      float2 xo = x[k];
      float xnx = fmaxf(xo.x + tau*(1.0f - ax), 0.0f);
      float xny = fmaxf(xo.y + tau*(1.0f - ay), 0.0f);
      if (!last) z_s[cj[k]] = make_float2(2.0f*xnx - xo.x, 2.0f*xny - xo.y);
      x[k] = make_float2(xnx, xny);
    }
    if (last) break;
    __syncthreads();
    // dual: quarter-row gathers + in-wave reduce across q
    float ax = 0.0f, ay = 0.0f;
    for (int c = 0; c < dt; ++c){
      ushort4 ix = dstream[(db + c)*64 + l];
      float2 a0 = *(const float2*)(zb + ix.x);
      float2 a1 = *(const float2*)(zb + ix.y);
      float2 a2 = *(const float2*)(zb + ix.z);
      float2 a3 = *(const float2*)(zb + ix.w);
      ax += (a0.x + a1.x) + (a2.x + a3.x);
      ay += (a0.y + a1.y) + (a2.y + a3.y);
    }
    ax += __shfl_xor(ax, 1);  ay += __shfl_xor(ay, 1);
    ax += __shfl_xor(ax, 2);  ay += __shfl_xor(ay, 2);
    if (q == 0){
      yv.x = fmaxf(yv.x + sigma*(ax - bi.x), 0.0f);
      yv.y = fmaxf(yv.y + sigma*(ay - bi.y), 0.0f);
      y_s[rid] = yv;
    }
    __syncthreads();
  }

  #pragma unroll
  for (int k = 0; k < 4; ++k){
    out[(size_t)b0*N + cj[k]]     = x[k].x;
    out[(size_t)(b0+1)*N + cj[k]] = x[k].y;
  }
}

// ---------------- launcher ----------------
extern "C" void kernel_launch(void* const* d_in, const int* in_sizes, int n_in,
                              void* d_out, int out_size, void* d_ws, size_t ws_size,
                              hipStream_t stream)
{
  const float* X = (const float*)d_in[0];   // [B, 16, 16] -> b
  const float* S = (const float*)d_in[1];   // [M, N]
  float* out = (float*)d_out;               // [B, N] fp32
  const int B = in_sizes[0] / M;            // 512

  char* p = (char*)d_ws;
  auto alloc = [&](size_t bytes)->char*{
    char* q = p; p += (bytes + 255) & ~size_t(255); return q;
  };
  int* col_cnt  = (int*)alloc(N*sizeof(int));
  int* col_perm = (int*)alloc(N*sizeof(int));
  int* col_rank = (int*)alloc(N*sizeof(int));
  int* row_cnt  = (int*)alloc(M*sizeof(int));
  int* row_perm = (int*)alloc(M*sizeof(int));
  int* row_rank = (int*)alloc(M*sizeof(int));
  int* pT4      = (int*)alloc(64*sizeof(int));
  int* pB4      = (int*)alloc(64*sizeof(int));
  int* dT4      = (int*)alloc(16*sizeof(int));
  int* dB4      = (int*)alloc(16*sizeof(int));
  float* tauw   = (float*)alloc(256);
  unsigned short* pstream = (unsigned short*)alloc(65536ull*8);
  unsigned short* dstream = (unsigned short*)alloc(81920ull*8);

  k_colcnt <<<N/256, 256, 0, stream>>>(S, col_cnt);
  k_rowcnt <<<16, 1024, 0, stream>>>(S, row_cnt);
  k_sortcol<<<N/256, 256, 0, stream>>>(col_cnt, col_perm, col_rank);
  k_sortrow<<<1, M, 0, stream>>>(row_cnt, row_perm, row_rank);
  k_trips  <<<1, 256, 0, stream>>>(col_cnt, col_perm, row_cnt, row_perm, pT4, pB4, dT4, dB4);
  k_fillp  <<<N/256, 256, 0, stream>>>(S, col_rank, pT4, pB4, pstream);
  k_filld  <<<M, 64, 0, stream>>>(S, row_cnt, row_perm, dT4, dB4, dstream);
  k_power  <<<1, 1024, 0, stream>>>((const ushort4*)pstream, (const ushort4*)dstream,
                                    col_perm, row_perm, pT4, pB4, dT4, dB4, tauw);
  k_main   <<<B/2, 1024, 0, stream>>>(X, (const ushort4*)pstream, (const ushort4*)dstream,
                                      col_perm, row_perm, pT4, pB4, dT4, dB4, tauw, out);
}